// Round 7
// baseline (163.750 us; speedup 1.0000x reference)
//
#include <hip/hip_runtime.h>
#include <hip/hip_bf16.h>

#define S_LEN 2048
#define E_DIM 512
#define D_DIM 64
#define H_NUM 8
#define B_NUM 2
#define BH_NUM 16
#define NQA 257
#define KSPLIT 4
#define KV_PER (S_LEN / KSPLIT)   // 512 keys per block
#define NT (KV_PER / 64)          // 8 tiles

typedef _Float16 half8 __attribute__((ext_vector_type(8)));
typedef _Float16 half4 __attribute__((ext_vector_type(4)));
typedef float f32x16 __attribute__((ext_vector_type(16)));
typedef unsigned int uint2v __attribute__((ext_vector_type(2)));
typedef unsigned int uint4v __attribute__((ext_vector_type(4)));

static __device__ __forceinline__ f32x16 MFMA(half8 a, half8 b, f32x16 c) {
    return __builtin_amdgcn_mfma_f32_32x32x16_f16(a, b, c, 0, 0, 0);
}
static __device__ __forceinline__ f32x16 ZERO16() {
    f32x16 z;
    #pragma unroll
    for (int i = 0; i < 16; ++i) z[i] = 0.f;
    return z;
}
// cvt_pkrtz returns __fp16x2; bit-cast to u32 immediately (same 4 bytes)
static __device__ __forceinline__ unsigned int PKRTZ(float a, float b) {
    return __builtin_bit_cast(unsigned int, __builtin_amdgcn_cvt_pkrtz(a, b));
}

// ---------------------------------------------------------------------------
// cast xs (fp32) -> Xh (fp16)
// ---------------------------------------------------------------------------
__global__ __launch_bounds__(256) void cast_x_kernel(
    const float* __restrict__ xs, _Float16* __restrict__ Xh)
{
    const int idx = (blockIdx.x * 256 + threadIdx.x) * 8;
    float4 a = *(const float4*)&xs[idx];
    float4 b = *(const float4*)&xs[idx + 4];
    half8 o;
    o[0] = (_Float16)a.x; o[1] = (_Float16)a.y; o[2] = (_Float16)a.z; o[3] = (_Float16)a.w;
    o[4] = (_Float16)b.x; o[5] = (_Float16)b.y; o[6] = (_Float16)b.z; o[7] = (_Float16)b.w;
    *(half8*)&Xh[idx] = o;
}

// ---------------------------------------------------------------------------
// cast + transpose weights -> Wht[type][h][n=64][k=512] fp16  (z = 0,1,2)
// z == 3: cast a_k -> fp16 (first 9 (y*8+x) blocks)
// ---------------------------------------------------------------------------
__global__ __launch_bounds__(256) void cast_wak_kernel(
    const float* __restrict__ w_q, const float* __restrict__ w_k,
    const float* __restrict__ w_v, const float* __restrict__ w_o,
    const float* __restrict__ a_k,
    _Float16* __restrict__ Wht, _Float16* __restrict__ akh)
{
    __shared__ float T[64][68];
    const int type = blockIdx.z;
    const int t = threadIdx.x;
    if (type == 3) {
        const int bn = blockIdx.y * 8 + blockIdx.x;
        if (bn >= 9) return;
        const int idx = (bn * 256 + t) * 8;
        if (idx < NQA * 64) {
            float4 a = *(const float4*)&a_k[idx];
            float4 b = *(const float4*)&a_k[idx + 4];
            half8 o;
            o[0] = (_Float16)a.x; o[1] = (_Float16)a.y; o[2] = (_Float16)a.z; o[3] = (_Float16)a.w;
            o[4] = (_Float16)b.x; o[5] = (_Float16)b.y; o[6] = (_Float16)b.z; o[7] = (_Float16)b.w;
            *(half8*)&akh[idx] = o;
        }
        return;
    }
    const int kt = blockIdx.x, h = blockIdx.y;
    const float* W = (type == 0) ? w_q : (type == 1) ? w_k : w_v;
    const float scale = (type == 0) ? 0.125f : (type == 2 ? w_o[h] : 1.0f);
    const int kr = t >> 2, nseg = (t & 3) * 16;
    #pragma unroll
    for (int i = 0; i < 4; ++i)
        *(float4*)&T[kr][nseg + 4 * i] =
            *(const float4*)&W[((size_t)h * 512 + kt * 64 + kr) * 64 + nseg + 4 * i];
    __syncthreads();
    const int nr = t >> 2, kseg = (t & 3) * 16;
    _Float16* dst = Wht + ((size_t)(type * 8 + h) * 64 + nr) * 512 + kt * 64 + kseg;
    #pragma unroll
    for (int i = 0; i < 2; ++i) {
        half8 o;
        #pragma unroll
        for (int j = 0; j < 8; ++j) o[j] = (_Float16)(T[kseg + 8 * i + j][nr] * scale);
        *(half8*)&dst[8 * i] = o;
    }
}

// ---------------------------------------------------------------------------
// MFMA projections: out[2048x64] = Xh[b] * Wht[type][h]^T   (K=512)
// grid (16 mtiles, 16 bh, 3 type), block 256 (4 waves x 32 rows)
// ---------------------------------------------------------------------------
__global__ __launch_bounds__(256) void proj_mfma_kernel(
    const _Float16* __restrict__ Xh, const _Float16* __restrict__ Wht,
    _Float16* __restrict__ Qh, _Float16* __restrict__ Kh,
    _Float16* __restrict__ Vt)
{
    __shared__ _Float16 Xlds[2][128][72];
    __shared__ _Float16 Wlds[2][64][72];

    const int mt = blockIdx.x, bh = blockIdx.y, type = blockIdx.z;
    const int b = bh >> 3, h = bh & 7;
    const int m0 = mt * 128;
    const int t = threadIdx.x, wid = t >> 6, lane = t & 63;
    const int lq = lane & 31, lh = lane >> 5;

    const _Float16* W = Wht + (size_t)(type * 8 + h) * 64 * 512;
    const _Float16* X = Xh + ((size_t)b * S_LEN + m0) * 512;

    const int xrow = t >> 1, xseg = (t & 1) * 32;
    const int wrow = t >> 2, wseg = (t & 3) * 16;

    #pragma unroll
    for (int i = 0; i < 4; ++i)
        *(half8*)&Xlds[0][xrow][xseg + 8 * i] =
            *(const half8*)&X[(size_t)xrow * 512 + xseg + 8 * i];
    #pragma unroll
    for (int i = 0; i < 2; ++i)
        *(half8*)&Wlds[0][wrow][wseg + 8 * i] =
            *(const half8*)&W[(size_t)wrow * 512 + wseg + 8 * i];
    __syncthreads();

    f32x16 acc[2];
    acc[0] = ZERO16(); acc[1] = ZERO16();
    int cur = 0;
    for (int c = 0; c < 8; ++c) {
        half8 xst[4], wst[2];
        if (c < 7) {
            const int k0 = (c + 1) * 64;
            #pragma unroll
            for (int i = 0; i < 4; ++i)
                xst[i] = *(const half8*)&X[(size_t)xrow * 512 + k0 + xseg + 8 * i];
            #pragma unroll
            for (int i = 0; i < 2; ++i)
                wst[i] = *(const half8*)&W[(size_t)wrow * 512 + k0 + wseg + 8 * i];
        }
        #pragma unroll
        for (int kc = 0; kc < 4; ++kc) {
            half8 a  = *(const half8*)&Xlds[cur][wid * 32 + lq][kc * 16 + lh * 8];
            half8 b0 = *(const half8*)&Wlds[cur][lq][kc * 16 + lh * 8];
            half8 b1 = *(const half8*)&Wlds[cur][32 + lq][kc * 16 + lh * 8];
            acc[0] = MFMA(a, b0, acc[0]);
            acc[1] = MFMA(a, b1, acc[1]);
        }
        if (c < 7) {
            #pragma unroll
            for (int i = 0; i < 4; ++i)
                *(half8*)&Xlds[cur ^ 1][xrow][xseg + 8 * i] = xst[i];
            #pragma unroll
            for (int i = 0; i < 2; ++i)
                *(half8*)&Wlds[cur ^ 1][wrow][wseg + 8 * i] = wst[i];
        }
        __syncthreads();
        cur ^= 1;
    }

    _Float16* ob = &Wlds[0][0][0];
    #pragma unroll
    for (int n = 0; n < 2; ++n)
        #pragma unroll
        for (int r = 0; r < 16; ++r) {
            int row = wid * 32 + (r & 3) + ((r >> 2) << 3) + (lh << 2);
            ob[row * 72 + n * 32 + lq] = (_Float16)acc[n][r];
        }
    __syncthreads();

    if (type == 2) {
        const int v = t >> 2, sseg = (t & 3) * 32;
        _Float16* dst = Vt + ((size_t)bh * 64 + v) * S_LEN + m0 + sseg;
        #pragma unroll
        for (int i = 0; i < 4; ++i) {
            half8 o;
            #pragma unroll
            for (int j = 0; j < 8; ++j) o[j] = ob[(sseg + 8 * i + j) * 72 + v];
            *(half8*)&dst[8 * i] = o;
        }
    } else {
        _Float16* P = (type == 0) ? Qh : Kh;
        const int row = t >> 1, seg = (t & 1) * 32;
        _Float16* dst = P + ((size_t)bh * S_LEN + m0 + row) * 64 + seg;
        #pragma unroll
        for (int i = 0; i < 4; ++i)
            *(half8*)&dst[8 * i] = *(const half8*)&ob[row * 72 + seg + 8 * i];
    }
}

// ---------------------------------------------------------------------------
// MFMA QA -> skew-stored bias:
//   Bb[bh][key][c2] = Q[q] . ak[256-c2]   with q = key + c2 - 128  (c2 in [0,256])
//   QLo[bh][q] = Q[q].ak[0]; QHi[bh][q] = Q[q].ak[256]
// Reads in attn (swapped layout) become lane-coalesced.
// ---------------------------------------------------------------------------
__global__ __launch_bounds__(256) void qa_mfma_kernel(
    const _Float16* __restrict__ Qh, const _Float16* __restrict__ akh,
    _Float16* __restrict__ Bb, _Float16* __restrict__ QLo,
    _Float16* __restrict__ QHi)
{
    __shared__ _Float16 ak[288][72];
    const int m0 = blockIdx.x * 128, bh = blockIdx.y;
    const int t = threadIdx.x, wid = t >> 6, lane = t & 63;
    const int lq = lane & 31, lh = lane >> 5;

    for (int r = t; r < 288; r += 256) {
        if (r < NQA) {
            #pragma unroll
            for (int i = 0; i < 8; ++i)
                *(half8*)&ak[r][8 * i] = *(const half8*)&akh[(size_t)r * 64 + 8 * i];
        } else {
            half8 z = {};
            #pragma unroll
            for (int i = 0; i < 8; ++i) *(half8*)&ak[r][8 * i] = z;
        }
    }
    __syncthreads();

    const int qg = m0 + wid * 32 + lq;
    half8 qfr[4];
    #pragma unroll
    for (int kc = 0; kc < 4; ++kc)
        qfr[kc] = *(const half8*)&Qh[((size_t)bh * S_LEN + qg) * 64 + kc * 16 + lh * 8];

    for (int nsub = 0; nsub < 9; ++nsub) {
        f32x16 acc = ZERO16();
        #pragma unroll
        for (int kc = 0; kc < 4; ++kc) {
            half8 bf = *(const half8*)&ak[nsub * 32 + lq][kc * 16 + lh * 8];
            acc = MFMA(qfr[kc], bf, acc);
        }
        const int col = nsub * 32 + lq;
        if (col < NQA) {
            #pragma unroll
            for (int r = 0; r < 16; ++r) {
                const int row = m0 + wid * 32 + (r & 3) + ((r >> 2) << 3) + (lh << 2);
                const _Float16 v = (_Float16)acc[r];
                const int key = row + col - 128;
                if (key >= 0 && key < S_LEN)
                    Bb[((size_t)bh * S_LEN + key) * NQA + (256 - col)] = v;
                if (col == 0)   QLo[(size_t)bh * S_LEN + row] = v;
                if (col == 256) QHi[(size_t)bh * S_LEN + row] = v;
            }
        }
    }
}

// ---------------------------------------------------------------------------
// Flash attention, 512-thread blocks (8 waves x 32 q-rows = 256 q-rows),
// KSPLIT=4, grid = 16 bh x 8 qt x 4 ks = 512 blocks (2/CU, XCD-swizzled).
// Bias: uniform tiles via softmax shift-trick; in-band tiles via coalesced
// skew-stored Bb reads with per-element clamp-select (beyond-clip pairs use
// the per-row endpoint biases qa_lo/qa_hi, which belong to THIS q-row).
// Writes Po[p][bh][q][v] fp16 + Ml[p][bh][q]=(m,l).
// ---------------------------------------------------------------------------
__global__ __launch_bounds__(512) void attn_kernel(
    const _Float16* __restrict__ Qh, const _Float16* __restrict__ Kh,
    const _Float16* __restrict__ Vt, const _Float16* __restrict__ Bb,
    const _Float16* __restrict__ QLo, const _Float16* __restrict__ QHi,
    _Float16* __restrict__ Po, float2* __restrict__ Ml)
{
    __shared__ __align__(16) char smraw[36864];
    _Float16 (*Klds)[64][72] = (_Float16(*)[64][72])smraw;             // [2][64][72]
    _Float16 (*Vlds)[64][72] = (_Float16(*)[64][72])(smraw + 18432);   // [2][64][72]
    _Float16* Obuf = (_Float16*)smraw;                                 // [256][72]

    const int p0 = blockIdx.x;                 // 0..511
    const int nb = (p0 & 7) * 64 + (p0 >> 3);  // XCD swizzle: 2 bh per XCD
    const int bh = nb >> 5;
    const int rem = nb & 31;
    const int qt = rem & 7, ks = rem >> 3;
    const int i0 = qt * 256, k0 = ks * KV_PER;

    const int t = threadIdx.x, wid = t >> 6, lane = t & 63;
    const int lq = lane & 31, lh = lane >> 5;
    const int i0w = i0 + wid * 32;             // this wave's 32 q-rows
    const int qg = i0w + lq;

    // block-uniform bias mode: 1 = all pairs clip at +128, 2 = all at -128
    int mode = 0;
    if (k0 >= i0 + 255 + 128) mode = 1;
    else if (k0 + KV_PER - 1 <= i0 - 128) mode = 2;

    half8 qf[4];
    #pragma unroll
    for (int kc = 0; kc < 4; ++kc)
        qf[kc] = *(const half8*)&Qh[((size_t)bh * S_LEN + qg) * 64 + kc * 16 + lh * 8];

    const float qa_lo = (float)QLo[(size_t)bh * S_LEN + qg];
    const float qa_hi = (float)QHi[(size_t)bh * S_LEN + qg];
    const _Float16* BbBase = Bb + (size_t)bh * S_LEN * NQA;

    float rm = -1e30f, rl = 0.f;
    f32x16 acco[2];
    acco[0] = ZERO16(); acco[1] = ZERO16();

    // staging: 512 threads, each 16B of K-tile and 16B of Vt-tile per KV tile
    const int srow = t >> 3, sseg = (t & 7) * 8;
    const _Float16* Kbase = Kh + ((size_t)bh * S_LEN + k0) * 64;
    const _Float16* Vbase = Vt + ((size_t)bh * 64 + srow) * S_LEN + k0;

    half8 kst, vst;
    // prologue: tile 0 -> buf0, tile 1 -> regs
    *(half8*)&Klds[0][srow][sseg] = *(const half8*)&Kbase[(size_t)srow * 64 + sseg];
    *(half8*)&Vlds[0][srow][sseg] = *(const half8*)&Vbase[sseg];
    kst = *(const half8*)&Kbase[(size_t)(64 + srow) * 64 + sseg];
    vst = *(const half8*)&Vbase[64 + sseg];
    __syncthreads();

    for (int jt = 0; jt < NT; ++jt) {
        const int cur = jt & 1;
        if (jt) __syncthreads();
        if (jt + 1 < NT) {                      // stage tile jt+1 -> other buf
            *(half8*)&Klds[cur ^ 1][srow][sseg] = kst;
            *(half8*)&Vlds[cur ^ 1][srow][sseg] = vst;
        }
        if (jt + 2 < NT) {                      // issue loads for tile jt+2
            const int jg = (jt + 2) * 64;
            kst = *(const half8*)&Kbase[(size_t)(jg + srow) * 64 + sseg];
            vst = *(const half8*)&Vbase[jg + sseg];
        }

        // S^T = K . Q^T
        f32x16 accs[2];
        accs[0] = ZERO16(); accs[1] = ZERO16();
        __builtin_amdgcn_s_setprio(1);
        #pragma unroll
        for (int kc = 0; kc < 4; ++kc) {
            half8 ka = *(const half8*)&Klds[cur][lq][kc * 16 + lh * 8];
            half8 kb = *(const half8*)&Klds[cur][32 + lq][kc * 16 + lh * 8];
            accs[0] = MFMA(ka, qf[kc], accs[0]);
            accs[1] = MFMA(kb, qf[kc], accs[1]);
        }
        __builtin_amdgcn_s_setprio(0);

        // bias: uniform tiles fold the constant into the softmax shift;
        // in-band tiles read skew-stored Bb (lane-coalesced), with
        // per-element select of qa_lo/qa_hi for beyond-clip pairs.
        const int j0g = k0 + jt * 64;
        const bool allhi = (mode == 1) || (mode == 0 && j0g >= i0w + 159);
        const bool alllo = (mode == 2) || (mode == 0 && j0g + 63 <= i0w - 128);
        float bunif = 0.f;
        if (allhi) bunif = qa_hi;
        else if (alllo) bunif = qa_lo;
        else {
            #pragma unroll
            for (int m = 0; m < 2; ++m)
                #pragma unroll
                for (int r = 0; r < 16; ++r) {
                    const int j = j0g + m * 32 + (r & 3) + ((r >> 2) << 3) + (lh << 2);
                    const int c2 = qg - j + 128;
                    const int c2c = min(max(c2, 0), 256);
                    float bv = (float)BbBase[(size_t)j * NQA + c2c];
                    // beyond-clip pairs need THIS row's endpoint bias, not the
                    // skew-stored neighbor row's value:
                    bv = (c2 < 0) ? qa_hi : ((c2 > 256) ? qa_lo : bv);
                    accs[m][r] += bv;
                }
        }

        // online softmax (lane owns q-row lq; lh halves synced via xor 32)
        float tmax = -1e30f;
        #pragma unroll
        for (int m = 0; m < 2; ++m)
            #pragma unroll
            for (int r = 0; r < 16; ++r) tmax = fmaxf(tmax, accs[m][r]);
        tmax = fmaxf(tmax, __shfl_xor(tmax, 32));
        const float mnew = fmaxf(rm, tmax + bunif);
        const float corr = __expf(rm - mnew);
        const float shift = mnew - bunif;
        rm = mnew;

        float psum = 0.f;
        #pragma unroll
        for (int m = 0; m < 2; ++m)
            #pragma unroll
            for (int r = 0; r < 16; ++r) {
                float p = __expf(accs[m][r] - shift);
                accs[m][r] = p;
                psum += p;
            }
        psum += __shfl_xor(psum, 32);
        rl = rl * corr + psum;
        #pragma unroll
        for (int n = 0; n < 2; ++n)
            #pragma unroll
            for (int r = 0; r < 16; ++r) acco[n][r] *= corr;

        // pack P -> PV B-fragments in-register (cvt_pkrtz + permlane32_swap)
        half8 pf[4];
        #pragma unroll
        for (int kc = 0; kc < 4; ++kc) {
            const int m = kc >> 1, rb = (kc & 1) * 8;
            unsigned int a01 = PKRTZ(accs[m][rb + 0], accs[m][rb + 1]);
            unsigned int a45 = PKRTZ(accs[m][rb + 4], accs[m][rb + 5]);
            unsigned int a23 = PKRTZ(accs[m][rb + 2], accs[m][rb + 3]);
            unsigned int a67 = PKRTZ(accs[m][rb + 6], accs[m][rb + 7]);
            uint2v r02 = __builtin_amdgcn_permlane32_swap(a01, a45, false, false);
            uint2v r13 = __builtin_amdgcn_permlane32_swap(a23, a67, false, false);
            uint4v wv;
            wv[0] = r02[0]; wv[1] = r13[0]; wv[2] = r02[1]; wv[3] = r13[1];
            pf[kc] = __builtin_bit_cast(half8, wv);
        }

        // O^T += V^T . P^T
        __builtin_amdgcn_s_setprio(1);
        #pragma unroll
        for (int kc = 0; kc < 4; ++kc) {
            half8 v0 = *(const half8*)&Vlds[cur][lq][kc * 16 + lh * 8];
            half8 v1 = *(const half8*)&Vlds[cur][32 + lq][kc * 16 + lh * 8];
            acco[0] = MFMA(v0, pf[kc], acco[0]);
            acco[1] = MFMA(v1, pf[kc], acco[1]);
        }
        __builtin_amdgcn_s_setprio(0);
    }

    // epilogue: all waves done with K/V LDS -> overlay O-buffer
    __syncthreads();
    const int orow = wid * 32 + lq;
    #pragma unroll
    for (int n = 0; n < 2; ++n)
        #pragma unroll
        for (int rq = 0; rq < 4; ++rq) {
            unsigned int p01 = PKRTZ(acco[n][rq * 4 + 0], acco[n][rq * 4 + 1]);
            unsigned int p23 = PKRTZ(acco[n][rq * 4 + 2], acco[n][rq * 4 + 3]);
            uint2v hv;
            hv[0] = p01; hv[1] = p23;
            *(uint2v*)&Obuf[(size_t)orow * 72 + n * 32 + rq * 8 + lh * 4] = hv;
        }
    if (lh == 0)
        Ml[((size_t)ks * BH_NUM + bh) * S_LEN + qg] = make_float2(rm, rl);
    // wave-synchronous LDS: each wave reads back only its own 32 rows
    asm volatile("s_waitcnt lgkmcnt(0)" ::: "memory");
    __builtin_amdgcn_sched_barrier(0);
    const int rrow = wid * 32 + (lane >> 1);
    const int rseg = (lane & 1) * 32;
    _Float16* dst = Po + (((size_t)ks * BH_NUM + bh) * S_LEN + i0 + rrow) * 64 + rseg;
    #pragma unroll
    for (int i = 0; i < 4; ++i)
        *(half8*)&dst[8 * i] = *(const half8*)&Obuf[(size_t)rrow * 72 + rseg + 8 * i];
}

// ---------------------------------------------------------------------------
// merge partials + combine heads:
// out[b][s][v] = sum_h (sum_p e^{m_p-M} O_p) / (sum_p e^{m_p-M} l_p)
// grid (64, 2), block 256: 32 s-rows x 8 v-groups of 8
// ---------------------------------------------------------------------------
__global__ __launch_bounds__(256) void merge_kernel(
    const _Float16* __restrict__ Po, const float2* __restrict__ Ml,
    float* __restrict__ out)
{
    const int b = blockIdx.y;
    const int s = blockIdx.x * 32 + (threadIdx.x >> 3);
    const int v0 = (threadIdx.x & 7) * 8;
    float acc[8] = {0, 0, 0, 0, 0, 0, 0, 0};
    #pragma unroll
    for (int h = 0; h < 8; ++h) {
        const int bh = b * 8 + h;
        float m[KSPLIT], l[KSPLIT];
        #pragma unroll
        for (int p = 0; p < KSPLIT; ++p) {
            const float2 v = Ml[((size_t)p * BH_NUM + bh) * S_LEN + s];
            m[p] = v.x; l[p] = v.y;
        }
        float M = fmaxf(fmaxf(m[0], m[1]), fmaxf(m[2], m[3]));
        float L = 0.f, w[KSPLIT];
        #pragma unroll
        for (int p = 0; p < KSPLIT; ++p) { w[p] = __expf(m[p] - M); L += w[p] * l[p]; }
        const float invL = 1.0f / L;
        #pragma unroll
        for (int p = 0; p < KSPLIT; ++p) {
            half8 o = *(const half8*)&Po[(((size_t)p * BH_NUM + bh) * S_LEN + s) * 64 + v0];
            const float wp = w[p] * invL;
            #pragma unroll
            for (int j = 0; j < 8; ++j) acc[j] += wp * (float)o[j];
        }
    }
    float4 o0 = {acc[0], acc[1], acc[2], acc[3]};
    float4 o1 = {acc[4], acc[5], acc[6], acc[7]};
    *(float4*)&out[((size_t)b * S_LEN + s) * 64 + v0] = o0;
    *(float4*)&out[((size_t)b * S_LEN + s) * 64 + v0 + 4] = o1;
}

// ---------------------------------------------------------------------------
extern "C" void kernel_launch(void* const* d_in, const int* in_sizes, int n_in,
                              void* d_out, int out_size, void* d_ws, size_t ws_size,
                              hipStream_t stream)
{
    const float* xs  = (const float*)d_in[0];
    const float* w_q = (const float*)d_in[1];
    const float* w_k = (const float*)d_in[2];
    const float* w_v = (const float*)d_in[3];
    const float* w_o = (const float*)d_in[4];
    const float* a_k = (const float*)d_in[5];
    float* out = (float*)d_out;

    char* w = (char*)d_ws;
    _Float16* Xh  = (_Float16*)w;  w += (size_t)B_NUM * S_LEN * E_DIM * 2;        // 4 MB
    _Float16* Wht = (_Float16*)w;  w += (size_t)3 * H_NUM * 64 * 512 * 2;         // 1.5 MB
    _Float16* akh = (_Float16*)w;  w += 33024;
    _Float16* Qh  = (_Float16*)w;  w += (size_t)BH_NUM * S_LEN * 64 * 2;
    _Float16* Kh  = (_Float16*)w;  w += (size_t)BH_NUM * S_LEN * 64 * 2;
    _Float16* Vt  = (_Float16*)w;  w += (size_t)BH_NUM * S_LEN * 64 * 2;
    _Float16* Bb  = (_Float16*)w;  w += (size_t)BH_NUM * S_LEN * NQA * 2;         // 16.9 MB
    _Float16* QLo = (_Float16*)w;  w += (size_t)BH_NUM * S_LEN * 2;
    _Float16* QHi = (_Float16*)w;  w += (size_t)BH_NUM * S_LEN * 2;
    _Float16* Po  = (_Float16*)w;  w += (size_t)KSPLIT * BH_NUM * S_LEN * 64 * 2; // 16.8 MB
    float2*   Ml  = (float2*)w;                                                    // 1 MB

    cast_x_kernel<<<1024, 256, 0, stream>>>(xs, Xh);
    cast_wak_kernel<<<dim3(8, 8, 4), 256, 0, stream>>>(w_q, w_k, w_v, w_o, a_k, Wht, akh);
    proj_mfma_kernel<<<dim3(16, 16, 3), 256, 0, stream>>>(Xh, Wht, Qh, Kh, Vt);
    qa_mfma_kernel<<<dim3(16, 16), 256, 0, stream>>>(Qh, akh, Bb, QLo, QHi);
    attn_kernel<<<512, 512, 0, stream>>>(Qh, Kh, Vt, Bb, QLo, QHi, Po, Ml);
    merge_kernel<<<dim3(64, 2), 256, 0, stream>>>(Po, Ml, out);
}

// Round 8
// 119.435 us; speedup vs baseline: 1.3710x; 1.3710x over previous
//
#include <hip/hip_runtime.h>
#include <hip/hip_bf16.h>

#define S_LEN 2048
#define E_DIM 512
#define D_DIM 64
#define H_NUM 8
#define B_NUM 2
#define BH_NUM 16
#define NQA 257
#define KSPLIT 4
#define KV_PER (S_LEN / KSPLIT)   // 512 keys per block
#define NT (KV_PER / 64)          // 8 tiles
#define QTILE 512                 // q-rows per block (16 waves x 32)

typedef _Float16 half8 __attribute__((ext_vector_type(8)));
typedef float f32x16 __attribute__((ext_vector_type(16)));
typedef unsigned int uint2v __attribute__((ext_vector_type(2)));
typedef unsigned int uint4v __attribute__((ext_vector_type(4)));

static __device__ __forceinline__ f32x16 MFMA(half8 a, half8 b, f32x16 c) {
    return __builtin_amdgcn_mfma_f32_32x32x16_f16(a, b, c, 0, 0, 0);
}
static __device__ __forceinline__ f32x16 ZERO16() {
    f32x16 z;
    #pragma unroll
    for (int i = 0; i < 16; ++i) z[i] = 0.f;
    return z;
}
static __device__ __forceinline__ unsigned int PKRTZ(float a, float b) {
    return __builtin_bit_cast(unsigned int, __builtin_amdgcn_cvt_pkrtz(a, b));
}

// ---------------------------------------------------------------------------
// cast xs (fp32) -> Xh (fp16)
// ---------------------------------------------------------------------------
__global__ __launch_bounds__(256) void cast_x_kernel(
    const float* __restrict__ xs, _Float16* __restrict__ Xh)
{
    const int idx = (blockIdx.x * 256 + threadIdx.x) * 8;
    float4 a = *(const float4*)&xs[idx];
    float4 b = *(const float4*)&xs[idx + 4];
    half8 o;
    o[0] = (_Float16)a.x; o[1] = (_Float16)a.y; o[2] = (_Float16)a.z; o[3] = (_Float16)a.w;
    o[4] = (_Float16)b.x; o[5] = (_Float16)b.y; o[6] = (_Float16)b.z; o[7] = (_Float16)b.w;
    *(half8*)&Xh[idx] = o;
}

// ---------------------------------------------------------------------------
// cast + transpose weights -> Wht[type][h][n=64][k=512] fp16  (z = 0,1,2)
// z == 3: cast a_k -> fp16 (first 9 (y*8+x) blocks)
// ---------------------------------------------------------------------------
__global__ __launch_bounds__(256) void cast_wak_kernel(
    const float* __restrict__ w_q, const float* __restrict__ w_k,
    const float* __restrict__ w_v, const float* __restrict__ w_o,
    const float* __restrict__ a_k,
    _Float16* __restrict__ Wht, _Float16* __restrict__ akh)
{
    __shared__ float T[64][68];
    const int type = blockIdx.z;
    const int t = threadIdx.x;
    if (type == 3) {
        const int bn = blockIdx.y * 8 + blockIdx.x;
        if (bn >= 9) return;
        const int idx = (bn * 256 + t) * 8;
        if (idx < NQA * 64) {
            float4 a = *(const float4*)&a_k[idx];
            float4 b = *(const float4*)&a_k[idx + 4];
            half8 o;
            o[0] = (_Float16)a.x; o[1] = (_Float16)a.y; o[2] = (_Float16)a.z; o[3] = (_Float16)a.w;
            o[4] = (_Float16)b.x; o[5] = (_Float16)b.y; o[6] = (_Float16)b.z; o[7] = (_Float16)b.w;
            *(half8*)&akh[idx] = o;
        }
        return;
    }
    const int kt = blockIdx.x, h = blockIdx.y;
    const float* W = (type == 0) ? w_q : (type == 1) ? w_k : w_v;
    const float scale = (type == 0) ? 0.125f : (type == 2 ? w_o[h] : 1.0f);
    const int kr = t >> 2, nseg = (t & 3) * 16;
    #pragma unroll
    for (int i = 0; i < 4; ++i)
        *(float4*)&T[kr][nseg + 4 * i] =
            *(const float4*)&W[((size_t)h * 512 + kt * 64 + kr) * 64 + nseg + 4 * i];
    __syncthreads();
    const int nr = t >> 2, kseg = (t & 3) * 16;
    _Float16* dst = Wht + ((size_t)(type * 8 + h) * 64 + nr) * 512 + kt * 64 + kseg;
    #pragma unroll
    for (int i = 0; i < 2; ++i) {
        half8 o;
        #pragma unroll
        for (int j = 0; j < 8; ++j) o[j] = (_Float16)(T[kseg + 8 * i + j][nr] * scale);
        *(half8*)&dst[8 * i] = o;
    }
}

// ---------------------------------------------------------------------------
// MFMA projections: out[2048x64] = Xh[b] * Wht[type][h]^T   (K=512)
// grid (16 mtiles, 16 bh, 3 type), block 256 (4 waves x 32 rows)
// ---------------------------------------------------------------------------
__global__ __launch_bounds__(256) void proj_mfma_kernel(
    const _Float16* __restrict__ Xh, const _Float16* __restrict__ Wht,
    _Float16* __restrict__ Qh, _Float16* __restrict__ Kh,
    _Float16* __restrict__ Vt)
{
    __shared__ _Float16 Xlds[2][128][72];
    __shared__ _Float16 Wlds[2][64][72];

    const int mt = blockIdx.x, bh = blockIdx.y, type = blockIdx.z;
    const int b = bh >> 3, h = bh & 7;
    const int m0 = mt * 128;
    const int t = threadIdx.x, wid = t >> 6, lane = t & 63;
    const int lq = lane & 31, lh = lane >> 5;

    const _Float16* W = Wht + (size_t)(type * 8 + h) * 64 * 512;
    const _Float16* X = Xh + ((size_t)b * S_LEN + m0) * 512;

    const int xrow = t >> 1, xseg = (t & 1) * 32;
    const int wrow = t >> 2, wseg = (t & 3) * 16;

    #pragma unroll
    for (int i = 0; i < 4; ++i)
        *(half8*)&Xlds[0][xrow][xseg + 8 * i] =
            *(const half8*)&X[(size_t)xrow * 512 + xseg + 8 * i];
    #pragma unroll
    for (int i = 0; i < 2; ++i)
        *(half8*)&Wlds[0][wrow][wseg + 8 * i] =
            *(const half8*)&W[(size_t)wrow * 512 + wseg + 8 * i];
    __syncthreads();

    f32x16 acc[2];
    acc[0] = ZERO16(); acc[1] = ZERO16();
    int cur = 0;
    for (int c = 0; c < 8; ++c) {
        half8 xst[4], wst[2];
        if (c < 7) {
            const int k0 = (c + 1) * 64;
            #pragma unroll
            for (int i = 0; i < 4; ++i)
                xst[i] = *(const half8*)&X[(size_t)xrow * 512 + k0 + xseg + 8 * i];
            #pragma unroll
            for (int i = 0; i < 2; ++i)
                wst[i] = *(const half8*)&W[(size_t)wrow * 512 + k0 + wseg + 8 * i];
        }
        #pragma unroll
        for (int kc = 0; kc < 4; ++kc) {
            half8 a  = *(const half8*)&Xlds[cur][wid * 32 + lq][kc * 16 + lh * 8];
            half8 b0 = *(const half8*)&Wlds[cur][lq][kc * 16 + lh * 8];
            half8 b1 = *(const half8*)&Wlds[cur][32 + lq][kc * 16 + lh * 8];
            acc[0] = MFMA(a, b0, acc[0]);
            acc[1] = MFMA(a, b1, acc[1]);
        }
        if (c < 7) {
            #pragma unroll
            for (int i = 0; i < 4; ++i)
                *(half8*)&Xlds[cur ^ 1][xrow][xseg + 8 * i] = xst[i];
            #pragma unroll
            for (int i = 0; i < 2; ++i)
                *(half8*)&Wlds[cur ^ 1][wrow][wseg + 8 * i] = wst[i];
        }
        __syncthreads();
        cur ^= 1;
    }

    _Float16* ob = &Wlds[0][0][0];
    #pragma unroll
    for (int n = 0; n < 2; ++n)
        #pragma unroll
        for (int r = 0; r < 16; ++r) {
            int row = wid * 32 + (r & 3) + ((r >> 2) << 3) + (lh << 2);
            ob[row * 72 + n * 32 + lq] = (_Float16)acc[n][r];
        }
    __syncthreads();

    if (type == 2) {
        const int v = t >> 2, sseg = (t & 3) * 32;
        _Float16* dst = Vt + ((size_t)bh * 64 + v) * S_LEN + m0 + sseg;
        #pragma unroll
        for (int i = 0; i < 4; ++i) {
            half8 o;
            #pragma unroll
            for (int j = 0; j < 8; ++j) o[j] = ob[(sseg + 8 * i + j) * 72 + v];
            *(half8*)&dst[8 * i] = o;
        }
    } else {
        _Float16* P = (type == 0) ? Qh : Kh;
        const int row = t >> 1, seg = (t & 1) * 32;
        _Float16* dst = P + ((size_t)bh * S_LEN + m0 + row) * 64 + seg;
        #pragma unroll
        for (int i = 0; i < 4; ++i)
            *(half8*)&dst[8 * i] = *(const half8*)&ob[row * 72 + seg + 8 * i];
    }
}

// ---------------------------------------------------------------------------
// MFMA QA: QAh[bh][s][r] = Qh[bh][s][:] . akh[r][:]   (fp16 out, coalesced)
// ---------------------------------------------------------------------------
__global__ __launch_bounds__(256) void qa_mfma_kernel(
    const _Float16* __restrict__ Qh, const _Float16* __restrict__ akh,
    _Float16* __restrict__ QAh)
{
    __shared__ _Float16 ak[288][72];
    const int m0 = blockIdx.x * 128, bh = blockIdx.y;
    const int t = threadIdx.x, wid = t >> 6, lane = t & 63;
    const int lq = lane & 31, lh = lane >> 5;

    for (int r = t; r < 288; r += 256) {
        if (r < NQA) {
            #pragma unroll
            for (int i = 0; i < 8; ++i)
                *(half8*)&ak[r][8 * i] = *(const half8*)&akh[(size_t)r * 64 + 8 * i];
        } else {
            half8 z = {};
            #pragma unroll
            for (int i = 0; i < 8; ++i) *(half8*)&ak[r][8 * i] = z;
        }
    }
    __syncthreads();

    const int qg = m0 + wid * 32 + lq;
    half8 qfr[4];
    #pragma unroll
    for (int kc = 0; kc < 4; ++kc)
        qfr[kc] = *(const half8*)&Qh[((size_t)bh * S_LEN + qg) * 64 + kc * 16 + lh * 8];

    for (int nsub = 0; nsub < 9; ++nsub) {
        f32x16 acc = ZERO16();
        #pragma unroll
        for (int kc = 0; kc < 4; ++kc) {
            half8 bf = *(const half8*)&ak[nsub * 32 + lq][kc * 16 + lh * 8];
            acc = MFMA(qfr[kc], bf, acc);
        }
        const int col = nsub * 32 + lq;
        if (col < NQA) {
            #pragma unroll
            for (int r = 0; r < 16; ++r) {
                int row = m0 + wid * 32 + (r & 3) + ((r >> 2) << 3) + (lh << 2);
                QAh[((size_t)bh * S_LEN + row) * NQA + col] = (_Float16)acc[r];
            }
        }
    }
}

// ---------------------------------------------------------------------------
// Flash attention, 1024-thread blocks (16 waves x 32 q-rows = 512 q-rows),
// KSPLIT=4, grid = 16 bh x 4 qt x 4 ks = 256 blocks (1/CU, XCD-swizzled).
// 4 waves/SIMD co-resident by construction (launch_bounds caps VGPR<=128).
// Waves 0-7 stage K, waves 8-15 stage V. Tree-reduced softmax with
// ballot-gated rescale skip. Writes Po[p][bh][q][v] fp16 + Ml=(m,l).
// ---------------------------------------------------------------------------
__global__ __launch_bounds__(1024, 1) void attn_kernel(
    const _Float16* __restrict__ Qh, const _Float16* __restrict__ Kh,
    const _Float16* __restrict__ Vt, const _Float16* __restrict__ QAh,
    _Float16* __restrict__ Po, float2* __restrict__ Ml)
{
    __shared__ __align__(16) char smraw[36864];
    _Float16 (*Klds)[64][72] = (_Float16(*)[64][72])smraw;             // [2][64][72]
    _Float16 (*Vlds)[64][72] = (_Float16(*)[64][72])(smraw + 18432);   // [2][64][72]
    _Float16* Obuf = (_Float16*)smraw;                                 // [256][72]

    const int p0 = blockIdx.x;                 // 0..255
    const int nb = (p0 & 7) * 32 + (p0 >> 3);  // XCD swizzle: 2 bh per XCD
    const int bh = nb >> 4;
    const int rem = nb & 15;
    const int qt = rem & 3, ks = rem >> 2;
    const int i0 = qt * QTILE, k0 = ks * KV_PER;

    const int t = threadIdx.x, wid = t >> 6, lane = t & 63;
    const int lq = lane & 31, lh = lane >> 5;
    const int i0w = i0 + wid * 32;             // this wave's 32 q-rows
    const int qg = i0w + lq;

    // block-uniform bias mode: 1 = all pairs clip at +128, 2 = all at -128
    int mode = 0;
    if (k0 >= i0 + QTILE + 127) mode = 1;          // k0 - (i0+511) >= 128
    else if (k0 + KV_PER - 1 <= i0 - 128) mode = 2;

    half8 qf[4];
    #pragma unroll
    for (int kc = 0; kc < 4; ++kc)
        qf[kc] = *(const half8*)&Qh[((size_t)bh * S_LEN + qg) * 64 + kc * 16 + lh * 8];

    const _Float16* qaRow = QAh + ((size_t)bh * S_LEN + qg) * NQA;
    const float qa_lo = (float)qaRow[0];
    const float qa_hi = (float)qaRow[256];

    float rm = -1e30f, rl = 0.f;
    f32x16 acco[2];
    acco[0] = ZERO16(); acco[1] = ZERO16();

    // staging: waves 0-7 stage K tile (16B/thread), waves 8-15 stage V tile
    const int t2 = t & 511;
    const int srow = t2 >> 3, sseg = (t2 & 7) * 8;
    const bool isK = (t < 512);
    const _Float16* Kbase = Kh + ((size_t)bh * S_LEN + k0) * 64;
    const _Float16* Vbase = Vt + ((size_t)bh * 64 + srow) * S_LEN + k0;

    half8 pre;
    if (isK) {
        *(half8*)&Klds[0][srow][sseg] = *(const half8*)&Kbase[(size_t)srow * 64 + sseg];
        pre = *(const half8*)&Kbase[(size_t)(64 + srow) * 64 + sseg];
    } else {
        *(half8*)&Vlds[0][srow][sseg] = *(const half8*)&Vbase[sseg];
        pre = *(const half8*)&Vbase[64 + sseg];
    }
    __syncthreads();

    for (int jt = 0; jt < NT; ++jt) {
        const int cur = jt & 1;
        if (jt) __syncthreads();
        if (jt + 1 < NT) {                      // stage tile jt+1 -> other buf
            if (isK) *(half8*)&Klds[cur ^ 1][srow][sseg] = pre;
            else     *(half8*)&Vlds[cur ^ 1][srow][sseg] = pre;
        }
        if (jt + 2 < NT) {                      // issue loads for tile jt+2
            const int jg = (jt + 2) * 64;
            pre = isK ? *(const half8*)&Kbase[(size_t)(jg + srow) * 64 + sseg]
                      : *(const half8*)&Vbase[jg + sseg];
        }

        // S^T = K . Q^T
        f32x16 accs[2];
        accs[0] = ZERO16(); accs[1] = ZERO16();
        __builtin_amdgcn_s_setprio(1);
        #pragma unroll
        for (int kc = 0; kc < 4; ++kc) {
            half8 ka = *(const half8*)&Klds[cur][lq][kc * 16 + lh * 8];
            half8 kb = *(const half8*)&Klds[cur][32 + lq][kc * 16 + lh * 8];
            accs[0] = MFMA(ka, qf[kc], accs[0]);
            accs[1] = MFMA(kb, qf[kc], accs[1]);
        }
        __builtin_amdgcn_s_setprio(0);

        // bias: uniform tiles fold into softmax shift; in-band tiles gather QA
        const int j0g = k0 + jt * 64;
        const bool allhi = (mode == 1) || (mode == 0 && j0g >= i0w + 159);
        const bool alllo = (mode == 2) || (mode == 0 && j0g + 63 <= i0w - 128);
        float bunif = 0.f;
        if (allhi) bunif = qa_hi;
        else if (alllo) bunif = qa_lo;
        else {
            #pragma unroll
            for (int m = 0; m < 2; ++m)
                #pragma unroll
                for (int r = 0; r < 16; ++r) {
                    const int j = j0g + m * 32 + (r & 3) + ((r >> 2) << 3) + (lh << 2);
                    const int idx = min(max(j - qg, -128), 128) + 128;
                    accs[m][r] += (float)qaRow[idx];
                }
        }

        // online softmax: tree max (depth 5 instead of serial 31)
        float t8[8];
        #pragma unroll
        for (int i = 0; i < 8; ++i)
            t8[i] = fmaxf(fmaxf(accs[0][i], accs[0][i + 8]),
                          fmaxf(accs[1][i], accs[1][i + 8]));
        float tmax = fmaxf(fmaxf(fmaxf(t8[0], t8[1]), fmaxf(t8[2], t8[3])),
                           fmaxf(fmaxf(t8[4], t8[5]), fmaxf(t8[6], t8[7])));
        tmax = fmaxf(tmax, __shfl_xor(tmax, 32));
        const float mnew = fmaxf(rm, tmax + bunif);
        const bool resc = __any(mnew > rm);     // wave-uniform
        const float corr = __expf(rm - mnew);
        const float shift = mnew - bunif;
        rm = mnew;

        #pragma unroll
        for (int m = 0; m < 2; ++m)
            #pragma unroll
            for (int r = 0; r < 16; ++r)
                accs[m][r] = __expf(accs[m][r] - shift);

        float s8[8];
        #pragma unroll
        for (int i = 0; i < 8; ++i)
            s8[i] = (accs[0][i] + accs[0][i + 8]) + (accs[1][i] + accs[1][i + 8]);
        float psum = ((s8[0] + s8[1]) + (s8[2] + s8[3])) +
                     ((s8[4] + s8[5]) + (s8[6] + s8[7]));
        psum += __shfl_xor(psum, 32);

        if (resc) {
            rl = rl * corr + psum;
            #pragma unroll
            for (int n = 0; n < 2; ++n)
                #pragma unroll
                for (int r = 0; r < 16; ++r) acco[n][r] *= corr;
        } else {
            rl += psum;
        }

        // pack P -> PV B-fragments in-register (cvt_pkrtz + permlane32_swap)
        half8 pf[4];
        #pragma unroll
        for (int kc = 0; kc < 4; ++kc) {
            const int m = kc >> 1, rb = (kc & 1) * 8;
            unsigned int a01 = PKRTZ(accs[m][rb + 0], accs[m][rb + 1]);
            unsigned int a45 = PKRTZ(accs[m][rb + 4], accs[m][rb + 5]);
            unsigned int a23 = PKRTZ(accs[m][rb + 2], accs[m][rb + 3]);
            unsigned int a67 = PKRTZ(accs[m][rb + 6], accs[m][rb + 7]);
            uint2v r02 = __builtin_amdgcn_permlane32_swap(a01, a45, false, false);
            uint2v r13 = __builtin_amdgcn_permlane32_swap(a23, a67, false, false);
            uint4v wv;
            wv[0] = r02[0]; wv[1] = r13[0]; wv[2] = r02[1]; wv[3] = r13[1];
            pf[kc] = __builtin_bit_cast(half8, wv);
        }

        // O^T += V^T . P^T
        __builtin_amdgcn_s_setprio(1);
        #pragma unroll
        for (int kc = 0; kc < 4; ++kc) {
            half8 v0 = *(const half8*)&Vlds[cur][lq][kc * 16 + lh * 8];
            half8 v1 = *(const half8*)&Vlds[cur][32 + lq][kc * 16 + lh * 8];
            acco[0] = MFMA(v0, pf[kc], acco[0]);
            acco[1] = MFMA(v1, pf[kc], acco[1]);
        }
        __builtin_amdgcn_s_setprio(0);
    }

    // Ml store (no LDS dependency)
    if (lh == 0)
        Ml[((size_t)ks * BH_NUM + bh) * S_LEN + qg] = make_float2(rm, rl);

    // epilogue: two phases through the 256-row Obuf overlay
    const int crow = t >> 2;                    // 0..255
    const int cseg = (t & 3) * 16;
    #pragma unroll
    for (int phase = 0; phase < 2; ++phase) {
        __syncthreads();                        // K/V reads done / prev copy done
        if ((wid >> 3) == phase) {
            const int orow = (wid & 7) * 32 + lq;
            #pragma unroll
            for (int n = 0; n < 2; ++n)
                #pragma unroll
                for (int rq = 0; rq < 4; ++rq) {
                    uint2v hv;
                    hv[0] = PKRTZ(acco[n][rq * 4 + 0], acco[n][rq * 4 + 1]);
                    hv[1] = PKRTZ(acco[n][rq * 4 + 2], acco[n][rq * 4 + 3]);
                    *(uint2v*)&Obuf[(size_t)orow * 72 + n * 32 + rq * 8 + lh * 4] = hv;
                }
        }
        __syncthreads();
        const int qrow = i0 + phase * 256 + crow;
        _Float16* dst = Po + (((size_t)ks * BH_NUM + bh) * S_LEN + qrow) * 64 + cseg;
        *(half8*)&dst[0] = *(const half8*)&Obuf[(size_t)crow * 72 + cseg];
        *(half8*)&dst[8] = *(const half8*)&Obuf[(size_t)crow * 72 + cseg + 8];
    }
}

// ---------------------------------------------------------------------------
// merge partials + combine heads:
// out[b][s][v] = sum_h (sum_p e^{m_p-M} O_p) / (sum_p e^{m_p-M} l_p)
// ---------------------------------------------------------------------------
__global__ __launch_bounds__(256) void merge_kernel(
    const _Float16* __restrict__ Po, const float2* __restrict__ Ml,
    float* __restrict__ out)
{
    const int b = blockIdx.y;
    const int s = blockIdx.x * 32 + (threadIdx.x >> 3);
    const int v0 = (threadIdx.x & 7) * 8;
    float acc[8] = {0, 0, 0, 0, 0, 0, 0, 0};
    #pragma unroll
    for (int h = 0; h < 8; ++h) {
        const int bh = b * 8 + h;
        float m[KSPLIT], l[KSPLIT];
        #pragma unroll
        for (int p = 0; p < KSPLIT; ++p) {
            const float2 v = Ml[((size_t)p * BH_NUM + bh) * S_LEN + s];
            m[p] = v.x; l[p] = v.y;
        }
        float M = fmaxf(fmaxf(m[0], m[1]), fmaxf(m[2], m[3]));
        float L = 0.f, w[KSPLIT];
        #pragma unroll
        for (int p = 0; p < KSPLIT; ++p) { w[p] = __expf(m[p] - M); L += w[p] * l[p]; }
        const float invL = 1.0f / L;
        #pragma unroll
        for (int p = 0; p < KSPLIT; ++p) {
            half8 o = *(const half8*)&Po[(((size_t)p * BH_NUM + bh) * S_LEN + s) * 64 + v0];
            const float wp = w[p] * invL;
            #pragma unroll
            for (int j = 0; j < 8; ++j) acc[j] += wp * (float)o[j];
        }
    }
    float4 o0 = {acc[0], acc[1], acc[2], acc[3]};
    float4 o1 = {acc[4], acc[5], acc[6], acc[7]};
    *(float4*)&out[((size_t)b * S_LEN + s) * 64 + v0] = o0;
    *(float4*)&out[((size_t)b * S_LEN + s) * 64 + v0 + 4] = o1;
}

// ---------------------------------------------------------------------------
extern "C" void kernel_launch(void* const* d_in, const int* in_sizes, int n_in,
                              void* d_out, int out_size, void* d_ws, size_t ws_size,
                              hipStream_t stream)
{
    const float* xs  = (const float*)d_in[0];
    const float* w_q = (const float*)d_in[1];
    const float* w_k = (const float*)d_in[2];
    const float* w_v = (const float*)d_in[3];
    const float* w_o = (const float*)d_in[4];
    const float* a_k = (const float*)d_in[5];
    float* out = (float*)d_out;

    char* w = (char*)d_ws;
    _Float16* Xh  = (_Float16*)w;  w += (size_t)B_NUM * S_LEN * E_DIM * 2;        // 4 MB
    _Float16* Wht = (_Float16*)w;  w += (size_t)3 * H_NUM * 64 * 512 * 2;         // 1.5 MB
    _Float16* akh = (_Float16*)w;  w += 33024;
    _Float16* Qh  = (_Float16*)w;  w += (size_t)BH_NUM * S_LEN * 64 * 2;
    _Float16* Kh  = (_Float16*)w;  w += (size_t)BH_NUM * S_LEN * 64 * 2;
    _Float16* Vt  = (_Float16*)w;  w += (size_t)BH_NUM * S_LEN * 64 * 2;
    _Float16* QAh = (_Float16*)w;  w += (size_t)BH_NUM * S_LEN * NQA * 2;         // 16.8 MB
    _Float16* Po  = (_Float16*)w;  w += (size_t)KSPLIT * BH_NUM * S_LEN * 64 * 2; // 16.8 MB
    float2*   Ml  = (float2*)w;                                                    // 1 MB

    cast_x_kernel<<<1024, 256, 0, stream>>>(xs, Xh);
    cast_wak_kernel<<<dim3(8, 8, 4), 256, 0, stream>>>(w_q, w_k, w_v, w_o, a_k, Wht, akh);
    proj_mfma_kernel<<<dim3(16, 16, 3), 256, 0, stream>>>(Xh, Wht, Qh, Kh, Vt);
    qa_mfma_kernel<<<dim3(16, 16), 256, 0, stream>>>(Qh, akh, QAh);
    attn_kernel<<<256, 1024, 0, stream>>>(Qh, Kh, Vt, QAh, Po, Ml);
    merge_kernel<<<dim3(64, 2), 256, 0, stream>>>(Po, Ml, out);
}

// Round 9
// 89.175 us; speedup vs baseline: 1.8363x; 1.3393x over previous
//
#include <hip/hip_runtime.h>
#include <hip/hip_bf16.h>

#define S_LEN 2048
#define E_DIM 512
#define D_DIM 64
#define H_NUM 8
#define B_NUM 2
#define BH_NUM 16
#define NQA 257
#define QAE_W 512                 // clamp-extended QA row width
#define KSPLIT 2
#define KV_PER (S_LEN / KSPLIT)   // 1024 keys per block
#define NT (KV_PER / 64)          // 16 tiles
#define QTILE 256                 // q-rows per block (8 waves x 32)

typedef _Float16 half8 __attribute__((ext_vector_type(8)));
typedef float f32x16 __attribute__((ext_vector_type(16)));
typedef unsigned int uint2v __attribute__((ext_vector_type(2)));
typedef unsigned int uint4v __attribute__((ext_vector_type(4)));

static __device__ __forceinline__ f32x16 MFMA(half8 a, half8 b, f32x16 c) {
    return __builtin_amdgcn_mfma_f32_32x32x16_f16(a, b, c, 0, 0, 0);
}
static __device__ __forceinline__ f32x16 ZERO16() {
    f32x16 z;
    #pragma unroll
    for (int i = 0; i < 16; ++i) z[i] = 0.f;
    return z;
}
static __device__ __forceinline__ unsigned int PKRTZ(float a, float b) {
    return __builtin_bit_cast(unsigned int, __builtin_amdgcn_cvt_pkrtz(a, b));
}

// ---------------------------------------------------------------------------
// cast xs (fp32) -> Xh (fp16)
// ---------------------------------------------------------------------------
__global__ __launch_bounds__(256) void cast_x_kernel(
    const float* __restrict__ xs, _Float16* __restrict__ Xh)
{
    const int idx = (blockIdx.x * 256 + threadIdx.x) * 8;
    float4 a = *(const float4*)&xs[idx];
    float4 b = *(const float4*)&xs[idx + 4];
    half8 o;
    o[0] = (_Float16)a.x; o[1] = (_Float16)a.y; o[2] = (_Float16)a.z; o[3] = (_Float16)a.w;
    o[4] = (_Float16)b.x; o[5] = (_Float16)b.y; o[6] = (_Float16)b.z; o[7] = (_Float16)b.w;
    *(half8*)&Xh[idx] = o;
}

// ---------------------------------------------------------------------------
// cast + transpose weights -> Wht[type][h][n=64][k=512] fp16  (z = 0,1,2)
// z == 3: cast a_k -> fp16 (first 9 (y*8+x) blocks)
// ---------------------------------------------------------------------------
__global__ __launch_bounds__(256) void cast_wak_kernel(
    const float* __restrict__ w_q, const float* __restrict__ w_k,
    const float* __restrict__ w_v, const float* __restrict__ w_o,
    const float* __restrict__ a_k,
    _Float16* __restrict__ Wht, _Float16* __restrict__ akh)
{
    __shared__ float T[64][68];
    const int type = blockIdx.z;
    const int t = threadIdx.x;
    if (type == 3) {
        const int bn = blockIdx.y * 8 + blockIdx.x;
        if (bn >= 9) return;
        const int idx = (bn * 256 + t) * 8;
        if (idx < NQA * 64) {
            float4 a = *(const float4*)&a_k[idx];
            float4 b = *(const float4*)&a_k[idx + 4];
            half8 o;
            o[0] = (_Float16)a.x; o[1] = (_Float16)a.y; o[2] = (_Float16)a.z; o[3] = (_Float16)a.w;
            o[4] = (_Float16)b.x; o[5] = (_Float16)b.y; o[6] = (_Float16)b.z; o[7] = (_Float16)b.w;
            *(half8*)&akh[idx] = o;
        }
        return;
    }
    const int kt = blockIdx.x, h = blockIdx.y;
    const float* W = (type == 0) ? w_q : (type == 1) ? w_k : w_v;
    const float scale = (type == 0) ? 0.125f : (type == 2 ? w_o[h] : 1.0f);
    const int kr = t >> 2, nseg = (t & 3) * 16;
    #pragma unroll
    for (int i = 0; i < 4; ++i)
        *(float4*)&T[kr][nseg + 4 * i] =
            *(const float4*)&W[((size_t)h * 512 + kt * 64 + kr) * 64 + nseg + 4 * i];
    __syncthreads();
    const int nr = t >> 2, kseg = (t & 3) * 16;
    _Float16* dst = Wht + ((size_t)(type * 8 + h) * 64 + nr) * 512 + kt * 64 + kseg;
    #pragma unroll
    for (int i = 0; i < 2; ++i) {
        half8 o;
        #pragma unroll
        for (int j = 0; j < 8; ++j) o[j] = (_Float16)(T[kseg + 8 * i + j][nr] * scale);
        *(half8*)&dst[8 * i] = o;
    }
}

// ---------------------------------------------------------------------------
// MFMA projections: out[2048x64] = Xh[b] * Wht[type][h]^T   (K=512)
// grid (16 mtiles, 16 bh, 3 type), block 256 (4 waves x 32 rows)
// ---------------------------------------------------------------------------
__global__ __launch_bounds__(256) void proj_mfma_kernel(
    const _Float16* __restrict__ Xh, const _Float16* __restrict__ Wht,
    _Float16* __restrict__ Qh, _Float16* __restrict__ Kh,
    _Float16* __restrict__ Vt)
{
    __shared__ _Float16 Xlds[2][128][72];
    __shared__ _Float16 Wlds[2][64][72];

    const int mt = blockIdx.x, bh = blockIdx.y, type = blockIdx.z;
    const int b = bh >> 3, h = bh & 7;
    const int m0 = mt * 128;
    const int t = threadIdx.x, wid = t >> 6, lane = t & 63;
    const int lq = lane & 31, lh = lane >> 5;

    const _Float16* W = Wht + (size_t)(type * 8 + h) * 64 * 512;
    const _Float16* X = Xh + ((size_t)b * S_LEN + m0) * 512;

    const int xrow = t >> 1, xseg = (t & 1) * 32;
    const int wrow = t >> 2, wseg = (t & 3) * 16;

    #pragma unroll
    for (int i = 0; i < 4; ++i)
        *(half8*)&Xlds[0][xrow][xseg + 8 * i] =
            *(const half8*)&X[(size_t)xrow * 512 + xseg + 8 * i];
    #pragma unroll
    for (int i = 0; i < 2; ++i)
        *(half8*)&Wlds[0][wrow][wseg + 8 * i] =
            *(const half8*)&W[(size_t)wrow * 512 + wseg + 8 * i];
    __syncthreads();

    f32x16 acc[2];
    acc[0] = ZERO16(); acc[1] = ZERO16();
    int cur = 0;
    for (int c = 0; c < 8; ++c) {
        half8 xst[4], wst[2];
        if (c < 7) {
            const int k0 = (c + 1) * 64;
            #pragma unroll
            for (int i = 0; i < 4; ++i)
                xst[i] = *(const half8*)&X[(size_t)xrow * 512 + k0 + xseg + 8 * i];
            #pragma unroll
            for (int i = 0; i < 2; ++i)
                wst[i] = *(const half8*)&W[(size_t)wrow * 512 + k0 + wseg + 8 * i];
        }
        #pragma unroll
        for (int kc = 0; kc < 4; ++kc) {
            half8 a  = *(const half8*)&Xlds[cur][wid * 32 + lq][kc * 16 + lh * 8];
            half8 b0 = *(const half8*)&Wlds[cur][lq][kc * 16 + lh * 8];
            half8 b1 = *(const half8*)&Wlds[cur][32 + lq][kc * 16 + lh * 8];
            acc[0] = MFMA(a, b0, acc[0]);
            acc[1] = MFMA(a, b1, acc[1]);
        }
        if (c < 7) {
            #pragma unroll
            for (int i = 0; i < 4; ++i)
                *(half8*)&Xlds[cur ^ 1][xrow][xseg + 8 * i] = xst[i];
            #pragma unroll
            for (int i = 0; i < 2; ++i)
                *(half8*)&Wlds[cur ^ 1][wrow][wseg + 8 * i] = wst[i];
        }
        __syncthreads();
        cur ^= 1;
    }

    _Float16* ob = &Wlds[0][0][0];
    #pragma unroll
    for (int n = 0; n < 2; ++n)
        #pragma unroll
        for (int r = 0; r < 16; ++r) {
            int row = wid * 32 + (r & 3) + ((r >> 2) << 3) + (lh << 2);
            ob[row * 72 + n * 32 + lq] = (_Float16)acc[n][r];
        }
    __syncthreads();

    if (type == 2) {
        const int v = t >> 2, sseg = (t & 3) * 32;
        _Float16* dst = Vt + ((size_t)bh * 64 + v) * S_LEN + m0 + sseg;
        #pragma unroll
        for (int i = 0; i < 4; ++i) {
            half8 o;
            #pragma unroll
            for (int j = 0; j < 8; ++j) o[j] = ob[(sseg + 8 * i + j) * 72 + v];
            *(half8*)&dst[8 * i] = o;
        }
    } else {
        _Float16* P = (type == 0) ? Qh : Kh;
        const int row = t >> 1, seg = (t & 1) * 32;
        _Float16* dst = P + ((size_t)bh * S_LEN + m0 + row) * 64 + seg;
        #pragma unroll
        for (int i = 0; i < 4; ++i)
            *(half8*)&dst[8 * i] = *(const half8*)&ob[row * 72 + seg + 8 * i];
    }
}

// ---------------------------------------------------------------------------
// MFMA QA -> clamp-extended table core region:
//   QAe[bh][s][c'] with c' = idx + 128, idx in [0,256] (cols 128..384).
// ---------------------------------------------------------------------------
__global__ __launch_bounds__(256) void qa_mfma_kernel(
    const _Float16* __restrict__ Qh, const _Float16* __restrict__ akh,
    _Float16* __restrict__ QAe)
{
    __shared__ _Float16 ak[288][72];
    const int m0 = blockIdx.x * 128, bh = blockIdx.y;
    const int t = threadIdx.x, wid = t >> 6, lane = t & 63;
    const int lq = lane & 31, lh = lane >> 5;

    for (int r = t; r < 288; r += 256) {
        if (r < NQA) {
            #pragma unroll
            for (int i = 0; i < 8; ++i)
                *(half8*)&ak[r][8 * i] = *(const half8*)&akh[(size_t)r * 64 + 8 * i];
        } else {
            half8 z = {};
            #pragma unroll
            for (int i = 0; i < 8; ++i) *(half8*)&ak[r][8 * i] = z;
        }
    }
    __syncthreads();

    const int qg = m0 + wid * 32 + lq;
    half8 qfr[4];
    #pragma unroll
    for (int kc = 0; kc < 4; ++kc)
        qfr[kc] = *(const half8*)&Qh[((size_t)bh * S_LEN + qg) * 64 + kc * 16 + lh * 8];

    for (int nsub = 0; nsub < 9; ++nsub) {
        f32x16 acc = ZERO16();
        #pragma unroll
        for (int kc = 0; kc < 4; ++kc) {
            half8 bf = *(const half8*)&ak[nsub * 32 + lq][kc * 16 + lh * 8];
            acc = MFMA(qfr[kc], bf, acc);
        }
        const int col = nsub * 32 + lq;
        if (col < NQA) {
            #pragma unroll
            for (int r = 0; r < 16; ++r) {
                int row = m0 + wid * 32 + (r & 3) + ((r >> 2) << 3) + (lh << 2);
                QAe[((size_t)bh * S_LEN + row) * QAE_W + col + 128] = (_Float16)acc[r];
            }
        }
    }
}

// ---------------------------------------------------------------------------
// fill QAe clamp padding: [0,128) <- value at c'=128 (idx 0),
// [384,512) <- value at c'=384 (idx 256). grid 1024 x 256thr, 32 rows/block.
// ---------------------------------------------------------------------------
__global__ __launch_bounds__(256) void qae_fill_kernel(_Float16* __restrict__ QAe)
{
    const int row = blockIdx.x * 32 + (threadIdx.x >> 3);
    const int c = (threadIdx.x & 7) * 8;
    const size_t base = (size_t)row * QAE_W;
    const _Float16 lo = QAe[base + 128];
    const _Float16 hi = QAe[base + 384];
    half8 vlo, vhi;
    #pragma unroll
    for (int j = 0; j < 8; ++j) { vlo[j] = lo; vhi[j] = hi; }
    *(half8*)&QAe[base + c] = vlo;
    *(half8*)&QAe[base + 64 + c] = vlo;
    *(half8*)&QAe[base + 384 + c] = vhi;   // overwrites 384 with hi (identical)
    *(half8*)&QAe[base + 448 + c] = vhi;
}

// ---------------------------------------------------------------------------
// Flash attention, 512-thread blocks (8 waves x 32 q-rows = 256 q-rows),
// KSPLIT=2, grid = 16 bh x 8 qt x 2 ks = 256 blocks (1/CU, XCD-swizzled).
// In-band tiles: wave stages its 32-row x 128-wide QAe band into per-wave LDS
// with 8 coalesced 16B loads, then 32 cheap LDS u16 reads (diagonal, ~no
// conflicts). Clamp semantics live in the QAe padding, so no select logic.
// Uniform tiles fold the constant bias into the softmax shift.
// ---------------------------------------------------------------------------
__global__ __launch_bounds__(512) void attn_kernel(
    const _Float16* __restrict__ Qh, const _Float16* __restrict__ Kh,
    const _Float16* __restrict__ Vt, const _Float16* __restrict__ QAe,
    _Float16* __restrict__ Po, float2* __restrict__ Ml)
{
    __shared__ __align__(16) char smraw[36864];
    _Float16 (*Klds)[64][72] = (_Float16(*)[64][72])smraw;             // [2][64][72]
    _Float16 (*Vlds)[64][72] = (_Float16(*)[64][72])(smraw + 18432);   // [2][64][72]
    _Float16* Obuf = (_Float16*)smraw;                                 // [256][72]
    __shared__ __align__(16) _Float16 Bnd[8][32][128];                 // 64KB band

    const int p0 = blockIdx.x;                 // 0..255
    const int nb = (p0 & 7) * 32 + (p0 >> 3);  // XCD swizzle: 2 bh per XCD
    const int bh = nb >> 4;
    const int rem = nb & 15;
    const int qt = rem & 7, ks = rem >> 3;
    const int i0 = qt * QTILE, k0 = ks * KV_PER;

    const int t = threadIdx.x, wid = t >> 6, lane = t & 63;
    const int lq = lane & 31, lh = lane >> 5;
    const int i0w = i0 + wid * 32;             // this wave's 32 q-rows
    const int qg = i0w + lq;

    // block-uniform bias mode: 1 = all pairs clip at +128, 2 = all at -128
    int mode = 0;
    if (k0 >= i0 + QTILE - 1 + 128) mode = 1;
    else if (k0 + KV_PER - 1 <= i0 - 128) mode = 2;

    half8 qf[4];
    #pragma unroll
    for (int kc = 0; kc < 4; ++kc)
        qf[kc] = *(const half8*)&Qh[((size_t)bh * S_LEN + qg) * 64 + kc * 16 + lh * 8];

    const _Float16* qaeRow = QAe + ((size_t)bh * S_LEN + qg) * QAE_W;
    const float qa_lo = (float)qaeRow[128];   // idx 0
    const float qa_hi = (float)qaeRow[384];   // idx 256
    const _Float16* BndSrc = QAe + ((size_t)bh * S_LEN + i0w) * QAE_W;

    float rm = -1e30f, rl = 0.f;
    f32x16 acco[2];
    acco[0] = ZERO16(); acco[1] = ZERO16();

    // staging: 512 threads, each 16B of K-tile and 16B of Vt-tile per KV tile
    const int srow = t >> 3, sseg = (t & 7) * 8;
    const _Float16* Kbase = Kh + ((size_t)bh * S_LEN + k0) * 64;
    const _Float16* Vbase = Vt + ((size_t)bh * 64 + srow) * S_LEN + k0;

    half8 kst, vst;
    *(half8*)&Klds[0][srow][sseg] = *(const half8*)&Kbase[(size_t)srow * 64 + sseg];
    *(half8*)&Vlds[0][srow][sseg] = *(const half8*)&Vbase[sseg];
    kst = *(const half8*)&Kbase[(size_t)(64 + srow) * 64 + sseg];
    vst = *(const half8*)&Vbase[64 + sseg];
    __syncthreads();

    const int brow = lane >> 4;                // 0..3 (band stage row group)
    const int bcol = (lane & 15) * 8;          // band stage col (halves)

    for (int jt = 0; jt < NT; ++jt) {
        const int cur = jt & 1;
        if (jt) __syncthreads();
        if (jt + 1 < NT) {
            *(half8*)&Klds[cur ^ 1][srow][sseg] = kst;
            *(half8*)&Vlds[cur ^ 1][srow][sseg] = vst;
        }
        if (jt + 2 < NT) {
            const int jg = (jt + 2) * 64;
            kst = *(const half8*)&Kbase[(size_t)(jg + srow) * 64 + sseg];
            vst = *(const half8*)&Vbase[jg + sseg];
        }

        const int j0g = k0 + jt * 64;
        const int diff = j0g - i0w;
        const bool allhi = (mode == 1) || (diff >= 159);
        const bool alllo = (mode == 2) || (diff <= -191);
        const bool inband = !(allhi || alllo);
        const int cw0 = (diff + 225) & ~7;     // 16B-aligned band start (c')

        // stage this wave's 32x128 bias band (coalesced; clamp via padding)
        if (inband) {
            #pragma unroll
            for (int ps = 0; ps < 8; ++ps) {
                half8 v = *(const half8*)&BndSrc[(size_t)(ps * 4 + brow) * QAE_W + cw0 + bcol];
                *(half8*)&Bnd[wid][ps * 4 + brow][bcol] = v;
            }
        }

        // S^T = K . Q^T
        f32x16 accs[2];
        accs[0] = ZERO16(); accs[1] = ZERO16();
        __builtin_amdgcn_s_setprio(1);
        #pragma unroll
        for (int kc = 0; kc < 4; ++kc) {
            half8 ka = *(const half8*)&Klds[cur][lq][kc * 16 + lh * 8];
            half8 kb = *(const half8*)&Klds[cur][32 + lq][kc * 16 + lh * 8];
            accs[0] = MFMA(ka, qf[kc], accs[0]);
            accs[1] = MFMA(kb, qf[kc], accs[1]);
        }
        __builtin_amdgcn_s_setprio(0);

        float bunif = 0.f;
        if (allhi) bunif = qa_hi;
        else if (alllo) bunif = qa_lo;
        else {
            // wave-local: wait for this wave's Bnd writes
            asm volatile("s_waitcnt lgkmcnt(0)" ::: "memory");
            __builtin_amdgcn_sched_barrier(0);
            const int pb = diff + 256 - cw0 - lq;   // + keyoff in [0,127]
            #pragma unroll
            for (int m = 0; m < 2; ++m)
                #pragma unroll
                for (int r = 0; r < 16; ++r) {
                    const int keyoff = m * 32 + (r & 3) + ((r >> 2) << 3) + (lh << 2);
                    accs[m][r] += (float)Bnd[wid][lq][pb + keyoff];
                }
        }

        // online softmax: tree max, shift-folded uniform bias
        float t8[8];
        #pragma unroll
        for (int i = 0; i < 8; ++i)
            t8[i] = fmaxf(fmaxf(accs[0][i], accs[0][i + 8]),
                          fmaxf(accs[1][i], accs[1][i + 8]));
        float tmax = fmaxf(fmaxf(fmaxf(t8[0], t8[1]), fmaxf(t8[2], t8[3])),
                           fmaxf(fmaxf(t8[4], t8[5]), fmaxf(t8[6], t8[7])));
        tmax = fmaxf(tmax, __shfl_xor(tmax, 32));
        const float mnew = fmaxf(rm, tmax + bunif);
        const bool resc = __any(mnew > rm);
        const float corr = __expf(rm - mnew);
        const float shift = mnew - bunif;
        rm = mnew;

        #pragma unroll
        for (int m = 0; m < 2; ++m)
            #pragma unroll
            for (int r = 0; r < 16; ++r)
                accs[m][r] = __expf(accs[m][r] - shift);

        float s8[8];
        #pragma unroll
        for (int i = 0; i < 8; ++i)
            s8[i] = (accs[0][i] + accs[0][i + 8]) + (accs[1][i] + accs[1][i + 8]);
        float psum = ((s8[0] + s8[1]) + (s8[2] + s8[3])) +
                     ((s8[4] + s8[5]) + (s8[6] + s8[7]));
        psum += __shfl_xor(psum, 32);

        if (resc) {
            rl = rl * corr + psum;
            #pragma unroll
            for (int n = 0; n < 2; ++n)
                #pragma unroll
                for (int r = 0; r < 16; ++r) acco[n][r] *= corr;
        } else {
            rl += psum;
        }

        // pack P -> PV B-fragments in-register (cvt_pkrtz + permlane32_swap)
        half8 pf[4];
        #pragma unroll
        for (int kc = 0; kc < 4; ++kc) {
            const int m = kc >> 1, rb = (kc & 1) * 8;
            unsigned int a01 = PKRTZ(accs[m][rb + 0], accs[m][rb + 1]);
            unsigned int a45 = PKRTZ(accs[m][rb + 4], accs[m][rb + 5]);
            unsigned int a23 = PKRTZ(accs[m][rb + 2], accs[m][rb + 3]);
            unsigned int a67 = PKRTZ(accs[m][rb + 6], accs[m][rb + 7]);
            uint2v r02 = __builtin_amdgcn_permlane32_swap(a01, a45, false, false);
            uint2v r13 = __builtin_amdgcn_permlane32_swap(a23, a67, false, false);
            uint4v wv;
            wv[0] = r02[0]; wv[1] = r13[0]; wv[2] = r02[1]; wv[3] = r13[1];
            pf[kc] = __builtin_bit_cast(half8, wv);
        }

        // O^T += V^T . P^T
        __builtin_amdgcn_s_setprio(1);
        #pragma unroll
        for (int kc = 0; kc < 4; ++kc) {
            half8 v0 = *(const half8*)&Vlds[cur][lq][kc * 16 + lh * 8];
            half8 v1 = *(const half8*)&Vlds[cur][32 + lq][kc * 16 + lh * 8];
            acco[0] = MFMA(v0, pf[kc], acco[0]);
            acco[1] = MFMA(v1, pf[kc], acco[1]);
        }
        __builtin_amdgcn_s_setprio(0);
    }

    // epilogue: all waves done with K/V LDS -> overlay O-buffer
    __syncthreads();
    const int orow = wid * 32 + lq;
    #pragma unroll
    for (int n = 0; n < 2; ++n)
        #pragma unroll
        for (int rq = 0; rq < 4; ++rq) {
            uint2v hv;
            hv[0] = PKRTZ(acco[n][rq * 4 + 0], acco[n][rq * 4 + 1]);
            hv[1] = PKRTZ(acco[n][rq * 4 + 2], acco[n][rq * 4 + 3]);
            *(uint2v*)&Obuf[(size_t)orow * 72 + n * 32 + rq * 8 + lh * 4] = hv;
        }
    if (lh == 0)
        Ml[((size_t)ks * BH_NUM + bh) * S_LEN + qg] = make_float2(rm, rl);
    asm volatile("s_waitcnt lgkmcnt(0)" ::: "memory");
    __builtin_amdgcn_sched_barrier(0);
    const int rrow = wid * 32 + (lane >> 1);
    const int rseg = (lane & 1) * 32;
    _Float16* dst = Po + (((size_t)ks * BH_NUM + bh) * S_LEN + i0 + rrow) * 64 + rseg;
    #pragma unroll
    for (int i = 0; i < 4; ++i)
        *(half8*)&dst[8 * i] = *(const half8*)&Obuf[(size_t)rrow * 72 + rseg + 8 * i];
}

// ---------------------------------------------------------------------------
// merge partials + combine heads:
// out[b][s][v] = sum_h (sum_p e^{m_p-M} O_p) / (sum_p e^{m_p-M} l_p)
// ---------------------------------------------------------------------------
__global__ __launch_bounds__(256) void merge_kernel(
    const _Float16* __restrict__ Po, const float2* __restrict__ Ml,
    float* __restrict__ out)
{
    const int b = blockIdx.y;
    const int s = blockIdx.x * 32 + (threadIdx.x >> 3);
    const int v0 = (threadIdx.x & 7) * 8;
    float acc[8] = {0, 0, 0, 0, 0, 0, 0, 0};
    #pragma unroll
    for (int h = 0; h < 8; ++h) {
        const int bh = b * 8 + h;
        float m[KSPLIT], l[KSPLIT];
        #pragma unroll
        for (int p = 0; p < KSPLIT; ++p) {
            const float2 v = Ml[((size_t)p * BH_NUM + bh) * S_LEN + s];
            m[p] = v.x; l[p] = v.y;
        }
        float M = fmaxf(m[0], m[1]);
        float L = 0.f, w[KSPLIT];
        #pragma unroll
        for (int p = 0; p < KSPLIT; ++p) { w[p] = __expf(m[p] - M); L += w[p] * l[p]; }
        const float invL = 1.0f / L;
        #pragma unroll
        for (int p = 0; p < KSPLIT; ++p) {
            half8 o = *(const half8*)&Po[(((size_t)p * BH_NUM + bh) * S_LEN + s) * 64 + v0];
            const float wp = w[p] * invL;
            #pragma unroll
            for (int j = 0; j < 8; ++j) acc[j] += wp * (float)o[j];
        }
    }
    float4 o0 = {acc[0], acc[1], acc[2], acc[3]};
    float4 o1 = {acc[4], acc[5], acc[6], acc[7]};
    *(float4*)&out[((size_t)b * S_LEN + s) * 64 + v0] = o0;
    *(float4*)&out[((size_t)b * S_LEN + s) * 64 + v0 + 4] = o1;
}

// ---------------------------------------------------------------------------
extern "C" void kernel_launch(void* const* d_in, const int* in_sizes, int n_in,
                              void* d_out, int out_size, void* d_ws, size_t ws_size,
                              hipStream_t stream)
{
    const float* xs  = (const float*)d_in[0];
    const float* w_q = (const float*)d_in[1];
    const float* w_k = (const float*)d_in[2];
    const float* w_v = (const float*)d_in[3];
    const float* w_o = (const float*)d_in[4];
    const float* a_k = (const float*)d_in[5];
    float* out = (float*)d_out;

    char* w = (char*)d_ws;
    _Float16* Xh  = (_Float16*)w;  w += (size_t)B_NUM * S_LEN * E_DIM * 2;        // 4 MB
    _Float16* Wht = (_Float16*)w;  w += (size_t)3 * H_NUM * 64 * 512 * 2;         // 1.5 MB
    _Float16* akh = (_Float16*)w;  w += 33024;
    _Float16* Qh  = (_Float16*)w;  w += (size_t)BH_NUM * S_LEN * 64 * 2;
    _Float16* Kh  = (_Float16*)w;  w += (size_t)BH_NUM * S_LEN * 64 * 2;
    _Float16* Vt  = (_Float16*)w;  w += (size_t)BH_NUM * S_LEN * 64 * 2;
    _Float16* QAe = (_Float16*)w;  w += (size_t)BH_NUM * S_LEN * QAE_W * 2;       // 33.5 MB
    _Float16* Po  = (_Float16*)w;  w += (size_t)KSPLIT * BH_NUM * S_LEN * 64 * 2; // 8.4 MB
    float2*   Ml  = (float2*)w;                                                    // 0.5 MB

    cast_x_kernel<<<1024, 256, 0, stream>>>(xs, Xh);
    cast_wak_kernel<<<dim3(8, 8, 4), 256, 0, stream>>>(w_q, w_k, w_v, w_o, a_k, Wht, akh);
    proj_mfma_kernel<<<dim3(16, 16, 3), 256, 0, stream>>>(Xh, Wht, Qh, Kh, Vt);
    qa_mfma_kernel<<<dim3(16, 16), 256, 0, stream>>>(Qh, akh, QAe);
    qae_fill_kernel<<<1024, 256, 0, stream>>>(QAe);
    attn_kernel<<<256, 512, 0, stream>>>(Qh, Kh, Vt, QAe, Po, Ml);
    merge_kernel<<<dim3(64, 2), 256, 0, stream>>>(Po, Ml, out);
}